// Round 1
// baseline (2307.120 us; speedup 1.0000x reference)
//
#include <hip/hip_runtime.h>
#include <math.h>

#define SAI 9
#define NB  4
#define CK  64
#define CV  64
#define HW  1024           // 32*32
#define SHW (SAI*HW)       // 9216

// One wave (64 lanes) per query; 4 waves (4 queries) per block.
// Lane processes 4 consecutive key-pixels at a time (float4 coalesced loads).
// Softmax without max-subtraction: scores ~ N(0,64); |s| < ~60 so exp() is
// safe in fp32. Invalid (masked) keys contribute weight 0.
__global__ __launch_bounds__(256) void cfa_fwd(
    const float* __restrict__ keys,   // (SAI,B,CK,H,W)
    const float* __restrict__ vals,   // (SAI,B,CV,H,W)
    const float* __restrict__ query,  // (B,CK,H,W)
    const float* __restrict__ disp,   // (B,1,H,W)
    const int*   __restrict__ seq,    // (B,SAI,2)
    float* __restrict__ out)          // (B,CV,H,W)
{
    const int lane = threadIdx.x & 63;
    const int wave = threadIdx.x >> 6;
    const int gq   = blockIdx.x * 4 + wave;  // global query id in [0, B*HW)
    const int b    = gq >> 10;               // / HW
    const int p    = gq & 1023;              // % HW

    // q[c]: wave-uniform addresses (all lanes load the same value)
    float q[CK];
#pragma unroll
    for (int c = 0; c < CK; ++c)
        q[c] = query[(b * CK + c) * HW + p];

    float o[CV];
#pragma unroll
    for (int c = 0; c < CV; ++c) o[c] = 0.f;
    float lsum = 0.f;

    for (int s = 0; s < SAI; ++s) {
        // distance mask scale for this frame
        const float c0 = (float)seq[(b * SAI + s) * 2 + 0];
        const float c1 = (float)seq[(b * SAI + s) * 2 + 1];
        const float dist = sqrtf((c1 - 5.f) * (c1 - 5.f) + (c0 - 5.f) * (c0 - 5.f));

        const float* __restrict__ Kf = keys + (size_t)(s * NB + b) * CK * HW;
        const float* __restrict__ Vf = vals + (size_t)(s * NB + b) * CV * HW;

        for (int j = 0; j < HW / 256; ++j) {   // 4 iters: 64 lanes x 4 keys = 256 keys
            const int pk = 4 * lane + 256 * j;

            const float4 dv = *(const float4*)(disp + b * HW + pk);
            const bool v0 = fabsf(dist * dv.x) > 0.5f;
            const bool v1 = fabsf(dist * dv.y) > 0.5f;
            const bool v2 = fabsf(dist * dv.z) > 0.5f;
            const bool v3 = fabsf(dist * dv.w) > 0.5f;

            float s0 = 0.f, s1 = 0.f, s2 = 0.f, s3 = 0.f;
#pragma unroll
            for (int c = 0; c < CK; ++c) {
                const float4 kv = *(const float4*)(Kf + c * HW + pk);
                const float qc = q[c];
                s0 = fmaf(qc, kv.x, s0);
                s1 = fmaf(qc, kv.y, s1);
                s2 = fmaf(qc, kv.z, s2);
                s3 = fmaf(qc, kv.w, s3);
            }

            const float w0 = v0 ? __expf(s0) : 0.f;
            const float w1 = v1 ? __expf(s1) : 0.f;
            const float w2 = v2 ? __expf(s2) : 0.f;
            const float w3 = v3 ? __expf(s3) : 0.f;
            lsum += (w0 + w1) + (w2 + w3);

#pragma unroll
            for (int c = 0; c < CV; ++c) {
                const float4 vv = *(const float4*)(Vf + c * HW + pk);
                float acc = o[c];
                acc = fmaf(w0, vv.x, acc);
                acc = fmaf(w1, vv.y, acc);
                acc = fmaf(w2, vv.z, acc);
                acc = fmaf(w3, vv.w, acc);
                o[c] = acc;
            }
        }
    }

    // cross-lane combine: total weight
#pragma unroll
    for (int off = 32; off >= 1; off >>= 1)
        lsum += __shfl_xor(lsum, off, 64);

    // reduce each output channel across lanes; lane c keeps channel c
    float res = 0.f;
#pragma unroll
    for (int c = 0; c < CV; ++c) {
        float v = o[c];
#pragma unroll
        for (int off = 32; off >= 1; off >>= 1)
            v += __shfl_xor(v, off, 64);
        if (lane == c) res = v;
    }

    out[(b * CV + lane) * HW + p] = res / lsum;
}

extern "C" void kernel_launch(void* const* d_in, const int* in_sizes, int n_in,
                              void* d_out, int out_size, void* d_ws, size_t ws_size,
                              hipStream_t stream) {
    const float* keys  = (const float*)d_in[0];
    const float* vals  = (const float*)d_in[1];
    const float* query = (const float*)d_in[2];
    const float* disp  = (const float*)d_in[3];
    const int*   seq   = (const int*)d_in[4];
    float* out = (float*)d_out;

    const int n_queries = NB * HW;           // 4096
    dim3 grid(n_queries / 4);                // 4 waves/block, 1 query/wave
    dim3 block(256);
    hipLaunchKernelGGL(cfa_fwd, grid, block, 0, stream,
                       keys, vals, query, disp, seq, out);
}

// Round 2
// 255.401 us; speedup vs baseline: 9.0333x; 9.0333x over previous
//
#include <hip/hip_runtime.h>
#include <math.h>

#define SAI 9
#define NB  4
#define CK  64
#define CV  64
#define HW  1024
#define QTILE 32          // queries per block
#define KTILE 128         // keys per LDS tile
#define NQT (HW/QTILE)    // 32 query tiles

#define QSTR 36           // sQ row stride (words), 16B-aligned rows
#define WSTR 132          // sW row stride (words), 16B-aligned rows
#define CSTR 17           // combine-buffer stride (conflict-free b32)

typedef unsigned int u32;
__device__ __forceinline__ void gload_lds16(const float* g, float* l) {
    __builtin_amdgcn_global_load_lds(
        (const __attribute__((address_space(1))) u32*)g,
        (__attribute__((address_space(3))) u32*)l,
        16, 0, 0);
}

// Phase-1: thread (qg1 0..7, kg 0..31), 4q x 4k register tile -> S[32][128]
// Phase-2: thread (half, qg2 0..7, cg 0..15), 4q x 4c register tile, halves split keys
__global__ __launch_bounds__(256, 2) void cfa_tiled(
    const float* __restrict__ keys,   // (SAI,B,CK,H,W)
    const float* __restrict__ vals,   // (SAI,B,CV,H,W)
    const float* __restrict__ query,  // (B,CK,H,W)
    const float* __restrict__ disp,   // (B,1,H,W)
    const int*   __restrict__ seq,    // (B,SAI,2)
    float* __restrict__ numW,         // [SAI*NB*HW][CV] partials (split path)
    float* __restrict__ denW,         // [SAI*NB*HW]
    float* __restrict__ out,          // (B,CV,H,W) direct path
    int nS)                           // 1 = split path, SAI = direct path
{
    const int tid = threadIdx.x;
    const int qt  = blockIdx.x;       // 0..31
    const int b   = blockIdx.y;       // 0..3
    const int s0  = blockIdx.z;       // frame (split) or 0
    const int p0  = qt * QTILE;
    const bool direct = (nS == SAI);

    // K tile [64][128] (no pad: global_load_lds linear) unioned with
    // V tile transposed+swizzled [128][64]: word(p,c) at p*64 + ((c/4 ^ (p&15))*4 + c%4)
    __shared__ alignas(16) float sKV[8192];
    __shared__ alignas(16) float sQ[CK * QSTR];
    __shared__ alignas(16) float sW[QTILE * WSTR];
    __shared__ alignas(16) float sDisp[HW];
    __shared__ float sDen[QTILE];

    const int qg1 = tid >> 5;         // phase-1 query group
    const int kg  = tid & 31;         // phase-1 key group
    const int half = tid >> 7;        // phase-2 key half
    const int qg2  = (tid >> 4) & 7;  // phase-2 query group
    const int cg   = tid & 15;        // phase-2 channel group
    const int pp = tid & 63;          // V staging pixel lane
    const int cq = tid >> 6;          // V staging channel quad

    // ---- stage Q tile (transposed is not needed: same [c][pix] orientation) + disp
    {
#pragma unroll
        for (int i = 0; i < 2; ++i) {
            int idx = i * 256 + tid;          // 0..511
            int c = idx >> 3, q4 = idx & 7;
            float4 v = *(const float4*)(query + ((size_t)b * CK + c) * HW + p0 + q4 * 4);
            *(float4*)&sQ[c * QSTR + q4 * 4] = v;
        }
        float4 dv = *(const float4*)(disp + b * HW + tid * 4);
        *(float4*)&sDisp[tid * 4] = dv;
    }

    float acc[4][4];
#pragma unroll
    for (int i = 0; i < 4; ++i)
#pragma unroll
        for (int j = 0; j < 4; ++j) acc[i][j] = 0.f;
    float dacc[4] = {0.f, 0.f, 0.f, 0.f};

    for (int si = 0; si < nS; ++si) {
        const int s = s0 + si;
        const float d0 = (float)seq[(b * SAI + s) * 2 + 1] - 5.f;
        const float d1 = (float)seq[(b * SAI + s) * 2 + 0] - 5.f;
        const float dist = sqrtf(d0 * d0 + d1 * d1);
        const float* Kf = keys + ((size_t)(s * NB + b)) * CK * HW;
        const float* Vf = vals + ((size_t)(s * NB + b)) * CV * HW;

        for (int t = 0; t < HW / KTILE; ++t) {
            __syncthreads();   // sKV free (prev phase-2 / prologue done)

            // ---- async stage K tile -> sKV as K[c][128]
            {
                const float* Kt = Kf + t * KTILE;
                const int r = tid >> 5;            // 0..7
                const int gc = (tid & 31) * 4;
#pragma unroll
                for (int it = 0; it < 8; ++it) {
                    int c = it * 8 + r;
                    gload_lds16(Kt + (size_t)c * HW + gc, &sKV[it * 1024 + r * 128 + gc]);
                }
            }
            __syncthreads();   // drains vmcnt: K visible

            // ---- phase 1: S = Q.K^T for this tile
            float sc[4][4];
#pragma unroll
            for (int i = 0; i < 4; ++i)
#pragma unroll
                for (int j = 0; j < 4; ++j) sc[i][j] = 0.f;

#pragma unroll 8
            for (int c = 0; c < CK; ++c) {
                float4 qv = *(float4*)&sQ[c * QSTR + qg1 * 4];
                float4 kv = *(float4*)&sKV[c * 128 + kg * 4];
                const float qa[4] = {qv.x, qv.y, qv.z, qv.w};
#pragma unroll
                for (int i = 0; i < 4; ++i) {
                    sc[i][0] = fmaf(qa[i], kv.x, sc[i][0]);
                    sc[i][1] = fmaf(qa[i], kv.y, sc[i][1]);
                    sc[i][2] = fmaf(qa[i], kv.z, sc[i][2]);
                    sc[i][3] = fmaf(qa[i], kv.w, sc[i][3]);
                }
            }

            // ---- mask + exp -> W[q][k], den partials
            {
                float4 dv = *(float4*)&sDisp[t * KTILE + kg * 4];
                const float m0 = (fabsf(dist * dv.x) > 0.5f) ? 1.f : 0.f;
                const float m1 = (fabsf(dist * dv.y) > 0.5f) ? 1.f : 0.f;
                const float m2 = (fabsf(dist * dv.z) > 0.5f) ? 1.f : 0.f;
                const float m3 = (fabsf(dist * dv.w) > 0.5f) ? 1.f : 0.f;
#pragma unroll
                for (int i = 0; i < 4; ++i) {
                    float4 wv;
                    wv.x = m0 * __expf(sc[i][0]);
                    wv.y = m1 * __expf(sc[i][1]);
                    wv.z = m2 * __expf(sc[i][2]);
                    wv.w = m3 * __expf(sc[i][3]);
                    dacc[i] += (wv.x + wv.y) + (wv.z + wv.w);
                    *(float4*)&sW[(qg1 * 4 + i) * WSTR + kg * 4] = wv;
                }
            }
            __syncthreads();   // W visible; K reads done -> reuse sKV for V

            // ---- stage V transposed+swizzled: coalesced 4-row column reads
            {
#pragma unroll
                for (int it = 0; it < 8; ++it) {
                    int p  = (it & 1) * 64 + pp;            // 0..127
                    int c4 = (it >> 1) * 4 + cq;            // f4-col 0..15
                    const float* vp = Vf + (size_t)(c4 * 4) * HW + t * KTILE + p;
                    float4 vv;
                    vv.x = vp[0];
                    vv.y = vp[HW];
                    vv.z = vp[2 * HW];
                    vv.w = vp[3 * HW];
                    *(float4*)&sKV[p * 64 + ((c4 ^ (p & 15)) << 2)] = vv;
                }
            }
            __syncthreads();   // V visible

            // ---- phase 2: acc += W . V
#pragma unroll 4
            for (int kk = 0; kk < 64; kk += 4) {
                const int k0 = half * 64 + kk;
                float wq[4][4];
#pragma unroll
                for (int i = 0; i < 4; ++i)
                    *(float4*)&wq[i][0] = *(float4*)&sW[(qg2 * 4 + i) * WSTR + k0];
#pragma unroll
                for (int j4 = 0; j4 < 4; ++j4) {
                    const int k = k0 + j4;
                    float4 vv = *(float4*)&sKV[k * 64 + ((cg ^ (k & 15)) << 2)];
#pragma unroll
                    for (int i = 0; i < 4; ++i) {
                        acc[i][0] = fmaf(wq[i][j4], vv.x, acc[i][0]);
                        acc[i][1] = fmaf(wq[i][j4], vv.y, acc[i][1]);
                        acc[i][2] = fmaf(wq[i][j4], vv.z, acc[i][2]);
                        acc[i][3] = fmaf(wq[i][j4], vv.w, acc[i][3]);
                    }
                }
            }
        }
    }

    // ---- den: reduce over the 32 kg-lanes (stays inside each 32-lane half)
#pragma unroll
    for (int off = 16; off >= 1; off >>= 1)
#pragma unroll
        for (int i = 0; i < 4; ++i)
            dacc[i] += __shfl_xor(dacc[i], off, 64);
    if (kg == 0) {
#pragma unroll
        for (int i = 0; i < 4; ++i) {
            if (direct) sDen[qg1 * 4 + i] = dacc[i];
            else        denW[((size_t)(s0 * NB + b)) * HW + p0 + qg1 * 4 + i] = dacc[i];
        }
    }

    // ---- combine the two key-halves of acc (reuse sW as scratch)
    __syncthreads();
    const int t7 = tid & 127;
    if (half == 1) {
#pragma unroll
        for (int i = 0; i < 4; ++i)
#pragma unroll
            for (int j = 0; j < 4; ++j)
                sW[t7 * CSTR + i * 4 + j] = acc[i][j];
    }
    __syncthreads();
    if (half == 0) {
#pragma unroll
        for (int i = 0; i < 4; ++i)
#pragma unroll
            for (int j = 0; j < 4; ++j)
                acc[i][j] += sW[t7 * CSTR + i * 4 + j];

        if (direct) {
#pragma unroll
            for (int i = 0; i < 4; ++i) {
                const int q = qg2 * 4 + i;
                const float r = 1.f / sDen[q];
#pragma unroll
                for (int j = 0; j < 4; ++j) {
                    const int c = cg * 4 + j;
                    out[((size_t)b * CV + c) * HW + p0 + q] = acc[i][j] * r;
                }
            }
        } else {
#pragma unroll
            for (int i = 0; i < 4; ++i) {
                const int q = p0 + qg2 * 4 + i;
                float4 v; v.x = acc[i][0]; v.y = acc[i][1]; v.z = acc[i][2]; v.w = acc[i][3];
                *(float4*)&numW[(((size_t)(s0 * NB + b)) * HW + q) * CV + cg * 4] = v;
            }
        }
    }
}

__global__ __launch_bounds__(256) void cfa_reduce(
    const float* __restrict__ numW, const float* __restrict__ denW,
    float* __restrict__ out)
{
    const int tid = threadIdx.x;
    const int bid = blockIdx.x;            // 0..1023
    const int b = bid >> 8;
    const int p = (bid & 255) * 4 + (tid >> 6);
    const int c = tid & 63;
    float num = 0.f, den = 0.f;
#pragma unroll
    for (int s = 0; s < SAI; ++s) {
        num += numW[(((size_t)(s * NB + b)) * HW + p) * CV + c];
        den += denW[((size_t)(s * NB + b)) * HW + p];
    }
    out[((size_t)b * CV + c) * HW + p] = num / den;
}

extern "C" void kernel_launch(void* const* d_in, const int* in_sizes, int n_in,
                              void* d_out, int out_size, void* d_ws, size_t ws_size,
                              hipStream_t stream) {
    const float* keys  = (const float*)d_in[0];
    const float* vals  = (const float*)d_in[1];
    const float* query = (const float*)d_in[2];
    const float* disp  = (const float*)d_in[3];
    const int*   seq   = (const int*)d_in[4];
    float* out = (float*)d_out;

    const size_t numElems = (size_t)SAI * NB * HW * CV;   // 2.36M
    const size_t denElems = (size_t)SAI * NB * HW;        // 36.9K
    const size_t need = (numElems + denElems) * sizeof(float);  // ~9.6 MB

    if (ws_size >= need) {
        float* numW = (float*)d_ws;
        float* denW = numW + numElems;
        dim3 grid(NQT, NB, SAI);
        hipLaunchKernelGGL(cfa_tiled, grid, dim3(256), 0, stream,
                           keys, vals, query, disp, seq, numW, denW, (float*)nullptr, 1);
        hipLaunchKernelGGL(cfa_reduce, dim3(1024), dim3(256), 0, stream,
                           numW, denW, out);
    } else {
        dim3 grid(NQT, NB, 1);
        hipLaunchKernelGGL(cfa_tiled, grid, dim3(256), 0, stream,
                           keys, vals, query, disp, seq,
                           (float*)nullptr, (float*)nullptr, out, SAI);
    }
}

// Round 3
// 247.621 us; speedup vs baseline: 9.3171x; 1.0314x over previous
//
#include <hip/hip_runtime.h>
#include <math.h>

#define SAI 9
#define NB  4
#define CK  64
#define CV  64
#define HW  1024
#define KTILE 128

typedef __attribute__((ext_vector_type(8))) short bf16x8;
typedef __attribute__((ext_vector_type(4))) float f32x4;

__device__ __forceinline__ short f2bf(float x) {           // RNE fp32->bf16
    unsigned u = __float_as_uint(x);
    unsigned r = (u + 0x7fff + ((u >> 16) & 1)) >> 16;
    return (short)r;
}
__device__ __forceinline__ float bf2f(short s) {
    return __uint_as_float(((unsigned)(unsigned short)s) << 16);
}

// Block: 256 threads = 4 waves. 32 queries x (nS frames x 1024 keys).
// Per 128-key tile:
//   phase1: S[32q][128k] via mfma 16x16x32 bf16 (hi/lo split: 3 terms),
//           K B-frags loaded DIRECTLY from global (no LDS), Q A-frags in regs.
//   exp+mask -> W bf16 in LDS (swizzled [q][128k]); den accumulated fp32 in regs.
//   phase2: O += W.V via mfma; V staged bf16 transposed [c][128k] (swizzled).
// Wave roles: phase1 wave w owns keys w*32..w*32+31; phase2 wave w owns channels w*16..w*16+15.
__global__ __launch_bounds__(256, 3) void cfa_mfma(
    const float* __restrict__ keys,   // (SAI,B,CK,H,W)
    const float* __restrict__ vals,   // (SAI,B,CV,H,W)
    const float* __restrict__ query,  // (B,CK,H,W)
    const float* __restrict__ disp,   // (B,1,H,W)
    const int*   __restrict__ seq,    // (B,SAI,2)
    float* __restrict__ numW,         // [SAI*NB*HW][CV] (split path)
    float* __restrict__ denW,         // [SAI*NB*HW]
    float* __restrict__ out,          // (B,CV,H,W) (direct path)
    int nS)
{
    __shared__ alignas(16) unsigned int sV[CV * 64];  // 64 c-rows x 128 bf16 = 16KB, swizzled
    __shared__ alignas(16) unsigned int sW[32 * 64];  // 32 q-rows x 128 bf16 = 8KB, swizzled
    __shared__ float sDen[4 * 32];
    __shared__ float sDenTot[32];

    const int tid  = threadIdx.x;
    const int w    = tid >> 6;
    const int lane = tid & 63;
    const int l15  = lane & 15;
    const int quad = lane >> 4;
    const int b    = blockIdx.y;
    const int s0   = blockIdx.z;
    const int p0   = blockIdx.x * 32;
    const bool direct = (nS == SAI);

    // ---- Q A-frags (hi/lo), kept in registers for the whole kernel
    bf16x8 qhi[2][2], qlo[2][2];
#pragma unroll
    for (int qt = 0; qt < 2; ++qt)
#pragma unroll
        for (int ks = 0; ks < 2; ++ks)
#pragma unroll
            for (int j = 0; j < 8; ++j) {
                float x = query[(size_t)(b * CK + ks * 32 + quad * 8 + j) * HW + p0 + qt * 16 + l15];
                short h = f2bf(x);
                qhi[qt][ks][j] = h;
                qlo[qt][ks][j] = f2bf(x - bf2f(h));
            }

    f32x4 acc[2];
#pragma unroll
    for (int qt = 0; qt < 2; ++qt)
#pragma unroll
        for (int r = 0; r < 4; ++r) acc[qt][r] = 0.f;
    float denacc[2][4] = {{0.f,0.f,0.f,0.f},{0.f,0.f,0.f,0.f}};

    for (int si = 0; si < nS; ++si) {
        const int s = s0 + si;
        const float d0 = (float)seq[(b * SAI + s) * 2 + 0] - 5.f;
        const float d1 = (float)seq[(b * SAI + s) * 2 + 1] - 5.f;
        const float dist = sqrtf(d0 * d0 + d1 * d1);
        const float* Kf = keys + (size_t)(s * NB + b) * CK * HW;
        const float* Vf = vals + (size_t)(s * NB + b) * CV * HW;

        for (int t = 0; t < HW / KTILE; ++t) {
            const int t128 = t * KTILE;
            __syncthreads();   // prev phase-2 reads of sV/sW done

            // ---- stage V: rows c = tid>>2, keys (tid&3)*32..+31, bf16 swizzled
            {
                const int c  = tid >> 2;
                const int kq = (tid & 3) * 32;
                const float* vp = Vf + (size_t)c * HW + t128 + kq;
                float vv[32];
#pragma unroll
                for (int i = 0; i < 8; ++i) {
                    float4 f = *(const float4*)(vp + i * 4);
                    vv[i*4+0] = f.x; vv[i*4+1] = f.y; vv[i*4+2] = f.z; vv[i*4+3] = f.w;
                }
#pragma unroll
                for (int gi = 0; gi < 4; ++gi) {
                    uint4 pk;
                    unsigned* pkp = (unsigned*)&pk;
#pragma unroll
                    for (int h2 = 0; h2 < 4; ++h2) {
                        unsigned lo = (unsigned)(unsigned short)f2bf(vv[gi*8 + h2*2]);
                        unsigned hi = (unsigned)(unsigned short)f2bf(vv[gi*8 + h2*2 + 1]);
                        pkp[h2] = lo | (hi << 16);
                    }
                    const int g = (kq >> 3) + gi;
                    *(uint4*)&sV[c * 64 + ((g ^ (c & 7)) << 2)] = pk;
                }
            }

            // ---- phase 1: S = Q.K^T, K B-frags direct from global
            f32x4 sc[2][2];
#pragma unroll
            for (int qt = 0; qt < 2; ++qt)
#pragma unroll
                for (int kt = 0; kt < 2; ++kt)
#pragma unroll
                    for (int r = 0; r < 4; ++r) sc[qt][kt][r] = 0.f;

            const int keyBase = t128 + w * 32 + l15;
#pragma unroll
            for (int kt = 0; kt < 2; ++kt)
#pragma unroll
                for (int ks = 0; ks < 2; ++ks) {
                    bf16x8 kh, kl;
#pragma unroll
                    for (int j = 0; j < 8; ++j) {
                        float x = Kf[(size_t)(ks * 32 + quad * 8 + j) * HW + keyBase + kt * 16];
                        short h = f2bf(x);
                        kh[j] = h;
                        kl[j] = f2bf(x - bf2f(h));
                    }
#pragma unroll
                    for (int qt = 0; qt < 2; ++qt) {
                        sc[qt][kt] = __builtin_amdgcn_mfma_f32_16x16x32_bf16(qhi[qt][ks], kh, sc[qt][kt], 0, 0, 0);
                        sc[qt][kt] = __builtin_amdgcn_mfma_f32_16x16x32_bf16(qhi[qt][ks], kl, sc[qt][kt], 0, 0, 0);
                        sc[qt][kt] = __builtin_amdgcn_mfma_f32_16x16x32_bf16(qlo[qt][ks], kh, sc[qt][kt], 0, 0, 0);
                    }
                }

            // ---- mask + exp -> W (bf16, swizzled), den partials in regs
#pragma unroll
            for (int kt = 0; kt < 2; ++kt) {
                const int kk = w * 32 + kt * 16 + l15;           // key within tile
                const float dv = disp[b * HW + t128 + kk];
                const float msk = (fabsf(dist * dv) > 0.5f) ? 1.f : 0.f;
                const int g = kk >> 3;
#pragma unroll
                for (int qt = 0; qt < 2; ++qt)
#pragma unroll
                    for (int r = 0; r < 4; ++r) {
                        const float e = msk * __expf(sc[qt][kt][r]);
                        denacc[qt][r] += e;
                        const int q = qt * 16 + quad * 4 + r;
                        ((unsigned short*)sW)[q * 128 + ((g ^ (q & 7)) << 3) + (kk & 7)] =
                            (unsigned short)f2bf(e);
                    }
            }
            __syncthreads();   // sW + sV visible

            // ---- phase 2: acc += W.V  (wave w: channels w*16..w*16+15, all 128 keys)
            const int c = w * 16 + l15;
#pragma unroll
            for (int ks2 = 0; ks2 < 4; ++ks2) {
                const int g = ks2 * 4 + quad;
                uint4 vr = *(const uint4*)&sV[c * 64 + ((g ^ (c & 7)) << 2)];
                bf16x8 vfrag = __builtin_bit_cast(bf16x8, vr);
#pragma unroll
                for (int qt = 0; qt < 2; ++qt) {
                    const int q = qt * 16 + l15;
                    uint4 wr = *(const uint4*)&sW[q * 64 + ((g ^ (q & 7)) << 2)];
                    bf16x8 wfrag = __builtin_bit_cast(bf16x8, wr);
                    acc[qt] = __builtin_amdgcn_mfma_f32_16x16x32_bf16(wfrag, vfrag, acc[qt], 0, 0, 0);
                }
            }
        }
    }

    // ---- den: butterfly over the 16 key-lanes (linear, so once at the end)
#pragma unroll
    for (int off = 1; off < 16; off <<= 1)
#pragma unroll
        for (int qt = 0; qt < 2; ++qt)
#pragma unroll
            for (int r = 0; r < 4; ++r)
                denacc[qt][r] += __shfl_xor(denacc[qt][r], off, 64);

    if (l15 == 0)
#pragma unroll
        for (int qt = 0; qt < 2; ++qt)
#pragma unroll
            for (int r = 0; r < 4; ++r)
                sDen[w * 32 + qt * 16 + quad * 4 + r] = denacc[qt][r];
    __syncthreads();

    if (tid < 32) {
        const float d = sDen[tid] + sDen[32 + tid] + sDen[64 + tid] + sDen[96 + tid];
        if (direct) sDenTot[tid] = d;
        else        denW[(size_t)(s0 * NB + b) * HW + p0 + tid] = d;
    }

    if (direct) {
        __syncthreads();
#pragma unroll
        for (int qt = 0; qt < 2; ++qt)
#pragma unroll
            for (int r = 0; r < 4; ++r) {
                const int q = qt * 16 + quad * 4 + r;
                const int c = w * 16 + l15;
                out[((size_t)b * CV + c) * HW + p0 + q] = acc[qt][r] / sDenTot[q];
            }
    } else {
#pragma unroll
        for (int qt = 0; qt < 2; ++qt)
#pragma unroll
            for (int r = 0; r < 4; ++r) {
                const int q = qt * 16 + quad * 4 + r;
                const int c = w * 16 + l15;
                numW[((size_t)(s0 * NB + b) * HW + p0 + q) * CV + c] = acc[qt][r];
            }
    }
}

__global__ __launch_bounds__(256) void cfa_reduce(
    const float* __restrict__ numW, const float* __restrict__ denW,
    float* __restrict__ out)
{
    const int tid = threadIdx.x;
    const int bid = blockIdx.x;            // 0..1023
    const int b = bid >> 8;
    const int p = (bid & 255) * 4 + (tid >> 6);
    const int c = tid & 63;
    float num = 0.f, den = 0.f;
#pragma unroll
    for (int s = 0; s < SAI; ++s) {
        num += numW[(((size_t)(s * NB + b)) * HW + p) * CV + c];
        den += denW[((size_t)(s * NB + b)) * HW + p];
    }
    out[((size_t)b * CV + c) * HW + p] = num / den;
}

extern "C" void kernel_launch(void* const* d_in, const int* in_sizes, int n_in,
                              void* d_out, int out_size, void* d_ws, size_t ws_size,
                              hipStream_t stream) {
    const float* keys  = (const float*)d_in[0];
    const float* vals  = (const float*)d_in[1];
    const float* query = (const float*)d_in[2];
    const float* disp  = (const float*)d_in[3];
    const int*   seq   = (const int*)d_in[4];
    float* out = (float*)d_out;

    const size_t numElems = (size_t)SAI * NB * HW * CV;
    const size_t denElems = (size_t)SAI * NB * HW;
    const size_t need = (numElems + denElems) * sizeof(float);   // ~9.6 MB

    if (ws_size >= need) {
        float* numW = (float*)d_ws;
        float* denW = numW + numElems;
        dim3 grid(HW / 32, NB, SAI);        // 32 x 4 x 9 = 1152 blocks
        hipLaunchKernelGGL(cfa_mfma, grid, dim3(256), 0, stream,
                           keys, vals, query, disp, seq, numW, denW, (float*)nullptr, 1);
        hipLaunchKernelGGL(cfa_reduce, dim3(1024), dim3(256), 0, stream,
                           numW, denW, out);
    } else {
        dim3 grid(HW / 32, NB, 1);
        hipLaunchKernelGGL(cfa_mfma, grid, dim3(256), 0, stream,
                           keys, vals, query, disp, seq,
                           (float*)nullptr, (float*)nullptr, out, SAI);
    }
}

// Round 4
// 214.927 us; speedup vs baseline: 10.7345x; 1.1521x over previous
//
#include <hip/hip_runtime.h>
#include <math.h>

#define SAI 9
#define NB  4
#define CK  64
#define CV  64
#define HW  1024
#define KTILE 128
#define RSTR 68    // LDS row stride in words (136 shorts = 272 B, 16B-aligned, pad kills conflicts)

typedef __attribute__((ext_vector_type(8))) short bf16x8;
typedef __attribute__((ext_vector_type(4))) float f32x4;

__device__ __forceinline__ short f2bf(float x) {           // RNE fp32->bf16
    unsigned u = __float_as_uint(x);
    unsigned r = (u + 0x7fff + ((u >> 16) & 1)) >> 16;
    return (short)r;
}
__device__ __forceinline__ float bf2f(short s) {
    return __uint_as_float(((unsigned)(unsigned short)s) << 16);
}
__device__ __forceinline__ unsigned pk2(float a, float b) {
    return (unsigned)(unsigned short)f2bf(a) | ((unsigned)(unsigned short)f2bf(b) << 16);
}

// Block: 256 threads = 4 waves; 32 queries x (nS frames x 1024 keys).
// phase1: S via mfma 16x16x32 bf16, hi/lo split (3 mfmas); K B-frags direct from global.
// exp+mask -> W bf16 in LDS (linear rows, stride 136 shorts); den in regs.
// phase2: O += W.V via mfma; V bf16 rows [c][128keys] in LDS (linear, same stride).
__global__ __launch_bounds__(256, 2) void cfa_mfma(
    const float* __restrict__ keys,   // (SAI,B,CK,H,W)
    const float* __restrict__ vals,   // (SAI,B,CV,H,W)
    const float* __restrict__ query,  // (B,CK,H,W)
    const float* __restrict__ disp,   // (B,1,H,W)
    const int*   __restrict__ seq,    // (B,SAI,2)
    float* __restrict__ numW,         // [SAI*NB*HW][CV] (split path)
    float* __restrict__ denW,         // [SAI*NB*HW]
    float* __restrict__ out,          // (B,CV,H,W) (direct path)
    int nS)
{
    __shared__ alignas(16) unsigned int sV[CV * RSTR];  // 64 rows x 128 bf16 (+pad)
    __shared__ alignas(16) unsigned int sW[32 * RSTR];  // 32 rows x 128 bf16 (+pad)
    __shared__ float sDen[4 * 32];
    __shared__ float sDenTot[32];

    const int tid  = threadIdx.x;
    const int w    = tid >> 6;
    const int lane = tid & 63;
    const int l15  = lane & 15;
    const int quad = lane >> 4;
    const int b    = blockIdx.y;
    const int s0   = blockIdx.z;
    const int p0   = blockIdx.x * 32;
    const bool direct = (nS == SAI);

    // ---- Q A-frags (hi/lo), live for the whole kernel (32 VGPRs)
    bf16x8 qhi[2][2], qlo[2][2];
#pragma unroll
    for (int qt = 0; qt < 2; ++qt)
#pragma unroll
        for (int ks = 0; ks < 2; ++ks)
#pragma unroll
            for (int j = 0; j < 8; ++j) {
                float x = query[(size_t)(b * CK + ks * 32 + quad * 8 + j) * HW + p0 + qt * 16 + l15];
                short h = f2bf(x);
                qhi[qt][ks][j] = h;
                qlo[qt][ks][j] = f2bf(x - bf2f(h));
            }

    f32x4 acc[2];
#pragma unroll
    for (int qt = 0; qt < 2; ++qt)
#pragma unroll
        for (int r = 0; r < 4; ++r) acc[qt][r] = 0.f;
    float denacc[2][4] = {{0.f,0.f,0.f,0.f},{0.f,0.f,0.f,0.f}};

    for (int si = 0; si < nS; ++si) {
        const int s = s0 + si;
        const float d0 = (float)seq[(b * SAI + s) * 2 + 0] - 5.f;
        const float d1 = (float)seq[(b * SAI + s) * 2 + 1] - 5.f;
        const float dist = sqrtf(d0 * d0 + d1 * d1);
        const float* Kf = keys + (size_t)(s * NB + b) * CK * HW;
        const float* Vf = vals + (size_t)(s * NB + b) * CV * HW;

        for (int t = 0; t < HW / KTILE; ++t) {
            const int t128 = t * KTILE;
            __syncthreads();   // prev phase-2 reads of sV/sW done

            // ---- stage V: granule = 8 consecutive keys of channel c (no transpose)
            // 1024 granules / 256 threads = 4 iters; 8 live floats max
#pragma unroll
            for (int it = 0; it < 4; ++it) {
                const int gidx = it * 256 + tid;     // 0..1023
                const int c = gidx >> 4;             // 0..63
                const int g = gidx & 15;             // 0..15
                const float* vp = Vf + (size_t)c * HW + t128 + g * 8;
                const float4 f0 = *(const float4*)(vp);
                const float4 f1 = *(const float4*)(vp + 4);
                uint4 pk;
                pk.x = pk2(f0.x, f0.y);
                pk.y = pk2(f0.z, f0.w);
                pk.z = pk2(f1.x, f1.y);
                pk.w = pk2(f1.z, f1.w);
                *(uint4*)&sV[c * RSTR + g * 4] = pk;
            }

            // ---- phase 1: S = Q.K^T, K B-frags direct from global
            f32x4 sc[2][2];
#pragma unroll
            for (int qt = 0; qt < 2; ++qt)
#pragma unroll
                for (int kt = 0; kt < 2; ++kt)
#pragma unroll
                    for (int r = 0; r < 4; ++r) sc[qt][kt][r] = 0.f;

            const int keyBase = t128 + w * 32 + l15;
#pragma unroll
            for (int kt = 0; kt < 2; ++kt)
#pragma unroll
                for (int ks = 0; ks < 2; ++ks) {
                    bf16x8 kh, kl;
#pragma unroll
                    for (int j = 0; j < 8; ++j) {
                        float x = Kf[(size_t)(ks * 32 + quad * 8 + j) * HW + keyBase + kt * 16];
                        short h = f2bf(x);
                        kh[j] = h;
                        kl[j] = f2bf(x - bf2f(h));
                    }
#pragma unroll
                    for (int qt = 0; qt < 2; ++qt) {
                        sc[qt][kt] = __builtin_amdgcn_mfma_f32_16x16x32_bf16(qhi[qt][ks], kh, sc[qt][kt], 0, 0, 0);
                        sc[qt][kt] = __builtin_amdgcn_mfma_f32_16x16x32_bf16(qhi[qt][ks], kl, sc[qt][kt], 0, 0, 0);
                        sc[qt][kt] = __builtin_amdgcn_mfma_f32_16x16x32_bf16(qlo[qt][ks], kh, sc[qt][kt], 0, 0, 0);
                    }
                }

            // ---- mask + exp -> W (bf16, linear padded rows), den partials in regs
#pragma unroll
            for (int kt = 0; kt < 2; ++kt) {
                const int kk = w * 32 + kt * 16 + l15;           // key within tile
                const float dv = disp[b * HW + t128 + kk];
                const float msk = (fabsf(dist * dv) > 0.5f) ? 1.f : 0.f;
#pragma unroll
                for (int qt = 0; qt < 2; ++qt)
#pragma unroll
                    for (int r = 0; r < 4; ++r) {
                        const float e = msk * __expf(sc[qt][kt][r]);
                        denacc[qt][r] += e;
                        const int q = qt * 16 + quad * 4 + r;
                        ((unsigned short*)sW)[q * (2 * RSTR) + kk] = (unsigned short)f2bf(e);
                    }
            }
            __syncthreads();   // sW + sV visible

            // ---- phase 2: acc += W.V  (wave w: channels w*16..w*16+15, all 128 keys)
            const int c = w * 16 + l15;
#pragma unroll
            for (int ks2 = 0; ks2 < 4; ++ks2) {
                const int g = ks2 * 4 + quad;
                uint4 vr = *(const uint4*)&sV[c * RSTR + g * 4];
                bf16x8 vfrag = __builtin_bit_cast(bf16x8, vr);
#pragma unroll
                for (int qt = 0; qt < 2; ++qt) {
                    const int q = qt * 16 + l15;
                    uint4 wr = *(const uint4*)&sW[q * RSTR + g * 4];
                    bf16x8 wfrag = __builtin_bit_cast(bf16x8, wr);
                    acc[qt] = __builtin_amdgcn_mfma_f32_16x16x32_bf16(wfrag, vfrag, acc[qt], 0, 0, 0);
                }
            }
        }
    }

    // ---- den: butterfly over the 16 key-lanes
#pragma unroll
    for (int off = 1; off < 16; off <<= 1)
#pragma unroll
        for (int qt = 0; qt < 2; ++qt)
#pragma unroll
            for (int r = 0; r < 4; ++r)
                denacc[qt][r] += __shfl_xor(denacc[qt][r], off, 64);

    if (l15 == 0)
#pragma unroll
        for (int qt = 0; qt < 2; ++qt)
#pragma unroll
            for (int r = 0; r < 4; ++r)
                sDen[w * 32 + qt * 16 + quad * 4 + r] = denacc[qt][r];
    __syncthreads();

    if (tid < 32) {
        const float d = sDen[tid] + sDen[32 + tid] + sDen[64 + tid] + sDen[96 + tid];
        if (direct) sDenTot[tid] = d;
        else        denW[(size_t)(s0 * NB + b) * HW + p0 + tid] = d;
    }

    if (direct) {
        __syncthreads();
#pragma unroll
        for (int qt = 0; qt < 2; ++qt)
#pragma unroll
            for (int r = 0; r < 4; ++r) {
                const int q = qt * 16 + quad * 4 + r;
                const int c = w * 16 + l15;
                out[((size_t)b * CV + c) * HW + p0 + q] = acc[qt][r] / sDenTot[q];
            }
    } else {
#pragma unroll
        for (int qt = 0; qt < 2; ++qt)
#pragma unroll
            for (int r = 0; r < 4; ++r) {
                const int q = qt * 16 + quad * 4 + r;
                const int c = w * 16 + l15;
                numW[((size_t)(s0 * NB + b) * HW + p0 + q) * CV + c] = acc[qt][r];
            }
    }
}

__global__ __launch_bounds__(256) void cfa_reduce(
    const float* __restrict__ numW, const float* __restrict__ denW,
    float* __restrict__ out)
{
    const int tid = threadIdx.x;
    const int bid = blockIdx.x;            // 0..1023
    const int b = bid >> 8;
    const int p = (bid & 255) * 4 + (tid >> 6);
    const int c = tid & 63;
    float num = 0.f, den = 0.f;
#pragma unroll
    for (int s = 0; s < SAI; ++s) {
        num += numW[(((size_t)(s * NB + b)) * HW + p) * CV + c];
        den += denW[((size_t)(s * NB + b)) * HW + p];
    }
    out[((size_t)b * CV + c) * HW + p] = num / den;
}

extern "C" void kernel_launch(void* const* d_in, const int* in_sizes, int n_in,
                              void* d_out, int out_size, void* d_ws, size_t ws_size,
                              hipStream_t stream) {
    const float* keys  = (const float*)d_in[0];
    const float* vals  = (const float*)d_in[1];
    const float* query = (const float*)d_in[2];
    const float* disp  = (const float*)d_in[3];
    const int*   seq   = (const int*)d_in[4];
    float* out = (float*)d_out;

    const size_t numElems = (size_t)SAI * NB * HW * CV;
    const size_t denElems = (size_t)SAI * NB * HW;
    const size_t need = (numElems + denElems) * sizeof(float);   // ~9.6 MB

    if (ws_size >= need) {
        float* numW = (float*)d_ws;
        float* denW = numW + numElems;
        dim3 grid(HW / 32, NB, SAI);        // 1152 blocks
        hipLaunchKernelGGL(cfa_mfma, grid, dim3(256), 0, stream,
                           keys, vals, query, disp, seq, numW, denW, (float*)nullptr, 1);
        hipLaunchKernelGGL(cfa_reduce, dim3(1024), dim3(256), 0, stream,
                           numW, denW, out);
    } else {
        dim3 grid(HW / 32, NB, 1);
        hipLaunchKernelGGL(cfa_mfma, grid, dim3(256), 0, stream,
                           keys, vals, query, disp, seq,
                           (float*)nullptr, (float*)nullptr, out, SAI);
    }
}

// Round 5
// 120.668 us; speedup vs baseline: 19.1196x; 1.7811x over previous
//
#include <hip/hip_runtime.h>
#include <math.h>

#define SAI 9
#define NB  4
#define CK  64
#define CV  64
#define HW  1024
#define RSW 136   // sW row stride in shorts (272 B = 17*16B)
#define RSTR 68   // fallback kernel LDS stride (words)

typedef __attribute__((ext_vector_type(8))) short bf16x8;
typedef __attribute__((ext_vector_type(4))) float f32x4;
typedef unsigned short u16;
typedef unsigned int u32;

__device__ __forceinline__ u16 f2bf(float x) {           // RNE fp32->bf16
    unsigned u = __float_as_uint(x);
    return (u16)((u + 0x7fff + ((u >> 16) & 1)) >> 16);
}
__device__ __forceinline__ float bf2f(u16 s) {
    return __uint_as_float(((unsigned)s) << 16);
}
__device__ __forceinline__ unsigned pk2(float a, float b) {
    return (unsigned)f2bf(a) | ((unsigned)f2bf(b) << 16);
}

// ---------------- prep: fp32 -> bf16 fragments in MFMA order ----------------
// K frag granule (per frame f): idx = gg*512 + lane*8 + j, gg = g16*2+ks,
//   holds K[c = ks*32 + (lane>>4)*8 + j][p = g16*16 + (lane&15)]  (hi and lo arrays)
// V frag granule: idx = gg*512 + lane*8 + j, gg = ks2g*4+cg,
//   holds V[p = ks2g*32 + (lane>>4)*8 + j][c = cg*16 + (lane&15)]
__global__ __launch_bounds__(256) void cfa_prep(
    const float* __restrict__ keys, const float* __restrict__ vals,
    u16* __restrict__ khi, u16* __restrict__ klo, u16* __restrict__ vbf)
{
    const int gid = blockIdx.x * 256 + threadIdx.x;
    const int isV = gid >= (SAI * NB * 8192);
    const int id  = isV ? gid - SAI * NB * 8192 : gid;
    const int f   = id >> 13;            // frame = s*NB+b
    const int r   = id & 8191;
    const int lane = r & 63;
    const int gg   = r >> 6;             // 0..127
    const int l15 = lane & 15, quad = lane >> 4;
    const size_t fb = (size_t)f * (64 * 1024);

    if (!isV) {
        const int p  = (gg >> 1) * 16 + l15;
        const int c0 = (gg & 1) * 32 + quad * 8;
        const float* src = keys + fb + (size_t)c0 * HW + p;
        float x[8];
#pragma unroll
        for (int j = 0; j < 8; ++j) x[j] = src[(size_t)j * HW];
        uint4 ph, pl;
        u32* php = (u32*)&ph; u32* plp = (u32*)&pl;
#pragma unroll
        for (int h2 = 0; h2 < 4; ++h2) {
            u16 h0 = f2bf(x[h2 * 2]),     h1 = f2bf(x[h2 * 2 + 1]);
            u16 l0 = f2bf(x[h2 * 2] - bf2f(h0));
            u16 l1 = f2bf(x[h2 * 2 + 1] - bf2f(h1));
            php[h2] = (u32)h0 | ((u32)h1 << 16);
            plp[h2] = (u32)l0 | ((u32)l1 << 16);
        }
        const size_t dst = fb + (size_t)gg * 512 + lane * 8;
        *(uint4*)&khi[dst] = ph;
        *(uint4*)&klo[dst] = pl;
    } else {
        const int p = (gg >> 2) * 32 + quad * 8;
        const int c = (gg & 3) * 16 + l15;
        const float* src = vals + fb + (size_t)c * HW + p;
        const float4 a = *(const float4*)src;
        const float4 b = *(const float4*)(src + 4);
        uint4 pv;
        pv.x = pk2(a.x, a.y); pv.y = pk2(a.z, a.w);
        pv.z = pk2(b.x, b.y); pv.w = pk2(b.z, b.w);
        *(uint4*)&vbf[fb + (size_t)gg * 512 + lane * 8] = pv;
    }
}

// ---------------- main: per (32q, b, s) block; K/V frags direct from global ----
// phase1: A=K (m=key), B=Q (n=query) -> C row=key(quad*4+r), col=q(l15)
//   => exp output packs as b64 stores into sW[q][k] (k-contiguous).
// phase2: A=W (m=q), B=V (n=c) -> acc row=q(quad*4+r), col=c(l15).
__global__ __launch_bounds__(256, 4) void cfa_main(
    const u16* __restrict__ khi, const u16* __restrict__ klo,
    const u16* __restrict__ vbf,
    const float* __restrict__ query, const float* __restrict__ disp,
    const int* __restrict__ seq,
    float* __restrict__ numW, float* __restrict__ denW)
{
    __shared__ alignas(16) u16 sW[32 * RSW];
    __shared__ float sDen[4 * 32];

    const int tid = threadIdx.x;
    const int w = tid >> 6;
    const int lane = tid & 63;
    const int l15 = lane & 15, quad = lane >> 4;
    const int qt = blockIdx.x;
    const int b  = blockIdx.y;
    const int s  = blockIdx.z;
    const int p0 = qt * 32;
    const int f  = s * NB + b;
    const size_t fb = (size_t)f * (64 * 1024);

    const float d0 = (float)seq[(b * SAI + s) * 2 + 0] - 5.f;
    const float d1 = (float)seq[(b * SAI + s) * 2 + 1] - 5.f;
    const float dist = sqrtf(d0 * d0 + d1 * d1);

    // Q B-frags (n=q -> l15, k=channel -> quad*8+j), hi/lo
    bf16x8 qh[2][2], ql[2][2];
#pragma unroll
    for (int q2 = 0; q2 < 2; ++q2)
#pragma unroll
        for (int ks = 0; ks < 2; ++ks)
#pragma unroll
            for (int j = 0; j < 8; ++j) {
                float x = query[(size_t)(b * CK + ks * 32 + quad * 8 + j) * HW + p0 + q2 * 16 + l15];
                u16 h = f2bf(x);
                qh[q2][ks][j] = (short)h;
                ql[q2][ks][j] = (short)f2bf(x - bf2f(h));
            }

    f32x4 acc[2];
#pragma unroll
    for (int q2 = 0; q2 < 2; ++q2)
#pragma unroll
        for (int r = 0; r < 4; ++r) acc[q2][r] = 0.f;
    float den[2] = {0.f, 0.f};

    for (int t = 0; t < 8; ++t) {
        __syncthreads();   // prev phase-2 reads of sW done

        // ---- phase 1: S^T tiles (wave w owns keys w*32..+31)
        f32x4 sc[2][2];
#pragma unroll
        for (int q2 = 0; q2 < 2; ++q2)
#pragma unroll
            for (int kt = 0; kt < 2; ++kt)
#pragma unroll
                for (int r = 0; r < 4; ++r) sc[q2][kt][r] = 0.f;

#pragma unroll
        for (int kt = 0; kt < 2; ++kt) {
            const int g16 = t * 8 + w * 2 + kt;
#pragma unroll
            for (int ks = 0; ks < 2; ++ks) {
                const size_t ka = fb + (size_t)(g16 * 2 + ks) * 512 + lane * 8;
                const bf16x8 kh = __builtin_bit_cast(bf16x8, *(const uint4*)&khi[ka]);
                const bf16x8 kl = __builtin_bit_cast(bf16x8, *(const uint4*)&klo[ka]);
#pragma unroll
                for (int q2 = 0; q2 < 2; ++q2) {
                    sc[q2][kt] = __builtin_amdgcn_mfma_f32_16x16x32_bf16(kh, qh[q2][ks], sc[q2][kt], 0, 0, 0);
                    sc[q2][kt] = __builtin_amdgcn_mfma_f32_16x16x32_bf16(kl, qh[q2][ks], sc[q2][kt], 0, 0, 0);
                    sc[q2][kt] = __builtin_amdgcn_mfma_f32_16x16x32_bf16(kh, ql[q2][ks], sc[q2][kt], 0, 0, 0);
                }
            }
        }

        // ---- mask + exp -> sW[q][k] (b64 packed stores), den partials
#pragma unroll
        for (int kt = 0; kt < 2; ++kt) {
            const int kb = t * 128 + w * 32 + kt * 16 + quad * 4;   // global key of r=0
            const float4 dv = *(const float4*)(disp + b * HW + kb);
            const float m0 = (fabsf(dist * dv.x) > 0.5f) ? 1.f : 0.f;
            const float m1 = (fabsf(dist * dv.y) > 0.5f) ? 1.f : 0.f;
            const float m2 = (fabsf(dist * dv.z) > 0.5f) ? 1.f : 0.f;
            const float m3 = (fabsf(dist * dv.w) > 0.5f) ? 1.f : 0.f;
#pragma unroll
            for (int q2 = 0; q2 < 2; ++q2) {
                const float e0 = m0 * __expf(sc[q2][kt][0]);
                const float e1 = m1 * __expf(sc[q2][kt][1]);
                const float e2 = m2 * __expf(sc[q2][kt][2]);
                const float e3 = m3 * __expf(sc[q2][kt][3]);
                den[q2] += (e0 + e1) + (e2 + e3);
                uint2 pk;
                pk.x = pk2(e0, e1);
                pk.y = pk2(e2, e3);
                *(uint2*)&sW[(q2 * 16 + l15) * RSW + w * 32 + kt * 16 + quad * 4] = pk;
            }
        }
        __syncthreads();   // sW visible

        // ---- phase 2: acc += W.V (wave w owns channels w*16..+15)
#pragma unroll
        for (int k2 = 0; k2 < 4; ++k2) {
            const size_t va = fb + (size_t)((t * 4 + k2) * 4 + w) * 512 + lane * 8;
            const bf16x8 vf = __builtin_bit_cast(bf16x8, *(const uint4*)&vbf[va]);
#pragma unroll
            for (int q2 = 0; q2 < 2; ++q2) {
                const bf16x8 wf = __builtin_bit_cast(bf16x8,
                    *(const uint4*)&sW[(q2 * 16 + l15) * RSW + k2 * 32 + quad * 8]);
                acc[q2] = __builtin_amdgcn_mfma_f32_16x16x32_bf16(wf, vf, acc[q2], 0, 0, 0);
            }
        }
    }

    // ---- den: per-lane partial covers (w,quad) keys; sum over quads, then waves
#pragma unroll
    for (int q2 = 0; q2 < 2; ++q2) {
        den[q2] += __shfl_xor(den[q2], 16, 64);
        den[q2] += __shfl_xor(den[q2], 32, 64);
    }
    if (quad == 0) {
#pragma unroll
        for (int q2 = 0; q2 < 2; ++q2)
            sDen[w * 32 + q2 * 16 + l15] = den[q2];
    }
    __syncthreads();
    if (tid < 32)
        denW[(size_t)f * HW + p0 + tid] =
            sDen[tid] + sDen[32 + tid] + sDen[64 + tid] + sDen[96 + tid];

    // ---- numW (coalesced: c = l15 fastest)
#pragma unroll
    for (int q2 = 0; q2 < 2; ++q2)
#pragma unroll
        for (int r = 0; r < 4; ++r) {
            const int q = q2 * 16 + quad * 4 + r;
            const int c = w * 16 + l15;
            numW[((size_t)f * HW + p0 + q) * CV + c] = acc[q2][r];
        }
}

// ---------------- reduce: sum 9 frame partials, divide ----------------
__global__ __launch_bounds__(256) void cfa_reduce(
    const float* __restrict__ numW, const float* __restrict__ denW,
    float* __restrict__ out)
{
    const int tid = threadIdx.x;
    const int bid = blockIdx.x;            // 0..1023
    const int b = bid >> 8;
    const int p = (bid & 255) * 4 + (tid >> 6);
    const int c = tid & 63;
    float num = 0.f, den = 0.f;
#pragma unroll
    for (int s = 0; s < SAI; ++s) {
        num += numW[(((size_t)(s * NB + b)) * HW + p) * CV + c];
        den += denW[((size_t)(s * NB + b)) * HW + p];
    }
    out[((size_t)b * CV + c) * HW + p] = num / den;
}

// ---------------- fallback (R4, proven): used if ws too small ----------------
__global__ __launch_bounds__(256, 2) void cfa_fb(
    const float* __restrict__ keys, const float* __restrict__ vals,
    const float* __restrict__ query, const float* __restrict__ disp,
    const int* __restrict__ seq,
    float* __restrict__ numW, float* __restrict__ denW,
    float* __restrict__ out, int nS)
{
    __shared__ alignas(16) unsigned int sV[CV * RSTR];
    __shared__ alignas(16) unsigned int sWb[32 * RSTR];
    __shared__ float sDen[4 * 32];
    __shared__ float sDenTot[32];

    const int tid  = threadIdx.x;
    const int w    = tid >> 6;
    const int lane = tid & 63;
    const int l15  = lane & 15;
    const int quad = lane >> 4;
    const int b    = blockIdx.y;
    const int s0   = blockIdx.z;
    const int p0   = blockIdx.x * 32;
    const bool direct = (nS == SAI);

    bf16x8 qhi[2][2], qlo[2][2];
#pragma unroll
    for (int qt = 0; qt < 2; ++qt)
#pragma unroll
        for (int ks = 0; ks < 2; ++ks)
#pragma unroll
            for (int j = 0; j < 8; ++j) {
                float x = query[(size_t)(b * CK + ks * 32 + quad * 8 + j) * HW + p0 + qt * 16 + l15];
                u16 h = f2bf(x);
                qhi[qt][ks][j] = (short)h;
                qlo[qt][ks][j] = (short)f2bf(x - bf2f(h));
            }

    f32x4 acc[2];
#pragma unroll
    for (int qt = 0; qt < 2; ++qt)
#pragma unroll
        for (int r = 0; r < 4; ++r) acc[qt][r] = 0.f;
    float denacc[2][4] = {{0.f,0.f,0.f,0.f},{0.f,0.f,0.f,0.f}};

    for (int si = 0; si < nS; ++si) {
        const int s = s0 + si;
        const float d0 = (float)seq[(b * SAI + s) * 2 + 0] - 5.f;
        const float d1 = (float)seq[(b * SAI + s) * 2 + 1] - 5.f;
        const float dist = sqrtf(d0 * d0 + d1 * d1);
        const float* Kf = keys + (size_t)(s * NB + b) * CK * HW;
        const float* Vf = vals + (size_t)(s * NB + b) * CV * HW;

        for (int t = 0; t < HW / 128; ++t) {
            const int t128 = t * 128;
            __syncthreads();
#pragma unroll
            for (int it = 0; it < 4; ++it) {
                const int gidx = it * 256 + tid;
                const int c = gidx >> 4;
                const int g = gidx & 15;
                const float* vp = Vf + (size_t)c * HW + t128 + g * 8;
                const float4 f0 = *(const float4*)(vp);
                const float4 f1 = *(const float4*)(vp + 4);
                uint4 pk;
                pk.x = pk2(f0.x, f0.y); pk.y = pk2(f0.z, f0.w);
                pk.z = pk2(f1.x, f1.y); pk.w = pk2(f1.z, f1.w);
                *(uint4*)&sV[c * RSTR + g * 4] = pk;
            }

            f32x4 sc[2][2];
#pragma unroll
            for (int qt = 0; qt < 2; ++qt)
#pragma unroll
                for (int kt = 0; kt < 2; ++kt)
#pragma unroll
                    for (int r = 0; r < 4; ++r) sc[qt][kt][r] = 0.f;

            const int keyBase = t128 + w * 32 + l15;
#pragma unroll
            for (int kt = 0; kt < 2; ++kt)
#pragma unroll
                for (int ks = 0; ks < 2; ++ks) {
                    bf16x8 kh, kl;
#pragma unroll
                    for (int j = 0; j < 8; ++j) {
                        float x = Kf[(size_t)(ks * 32 + quad * 8 + j) * HW + keyBase + kt * 16];
                        u16 h = f2bf(x);
                        kh[j] = (short)h;
                        kl[j] = (short)f2bf(x - bf2f(h));
                    }
#pragma unroll
                    for (int qt = 0; qt < 2; ++qt) {
                        sc[qt][kt] = __builtin_amdgcn_mfma_f32_16x16x32_bf16(qhi[qt][ks], kh, sc[qt][kt], 0, 0, 0);
                        sc[qt][kt] = __builtin_amdgcn_mfma_f32_16x16x32_bf16(qhi[qt][ks], kl, sc[qt][kt], 0, 0, 0);
                        sc[qt][kt] = __builtin_amdgcn_mfma_f32_16x16x32_bf16(qlo[qt][ks], kh, sc[qt][kt], 0, 0, 0);
                    }
                }

#pragma unroll
            for (int kt = 0; kt < 2; ++kt) {
                const int kk = w * 32 + kt * 16 + l15;
                const float dv = disp[b * HW + t128 + kk];
                const float msk = (fabsf(dist * dv) > 0.5f) ? 1.f : 0.f;
#pragma unroll
                for (int qt = 0; qt < 2; ++qt)
#pragma unroll
                    for (int r = 0; r < 4; ++r) {
                        const float e = msk * __expf(sc[qt][kt][r]);
                        denacc[qt][r] += e;
                        const int q = qt * 16 + quad * 4 + r;
                        ((u16*)sWb)[q * (2 * RSTR) + kk] = f2bf(e);
                    }
            }
            __syncthreads();

            const int c = w * 16 + l15;
#pragma unroll
            for (int ks2 = 0; ks2 < 4; ++ks2) {
                const int g = ks2 * 4 + quad;
                uint4 vr = *(uint4*)&sV[c * RSTR + g * 4];
                bf16x8 vfrag = __builtin_bit_cast(bf16x8, vr);
#pragma unroll
                for (int qt = 0; qt < 2; ++qt) {
                    const int q = qt * 16 + l15;
                    uint4 wr = *(uint4*)&sWb[q * RSTR + g * 4];
                    bf16x8 wfrag = __builtin_bit_cast(bf16x8, wr);
                    acc[qt] = __builtin_amdgcn_mfma_f32_16x16x32_bf16(wfrag, vfrag, acc[qt], 0, 0, 0);
                }
            }
        }
    }

#pragma unroll
    for (int off = 1; off < 16; off <<= 1)
#pragma unroll
        for (int qt = 0; qt < 2; ++qt)
#pragma unroll
            for (int r = 0; r < 4; ++r)
                denacc[qt][r] += __shfl_xor(denacc[qt][r], off, 64);

    if (l15 == 0)
#pragma unroll
        for (int qt = 0; qt < 2; ++qt)
#pragma unroll
            for (int r = 0; r < 4; ++r)
                sDen[w * 32 + qt * 16 + quad * 4 + r] = denacc[qt][r];
    __syncthreads();

    if (tid < 32) {
        const float d = sDen[tid] + sDen[32 + tid] + sDen[64 + tid] + sDen[96 + tid];
        if (direct) sDenTot[tid] = d;
        else        denW[(size_t)(s0 * NB + b) * HW + p0 + tid] = d;
    }

    if (direct) {
        __syncthreads();
#pragma unroll
        for (int qt = 0; qt < 2; ++qt)
#pragma unroll
            for (int r = 0; r < 4; ++r) {
                const int q = qt * 16 + quad * 4 + r;
                const int c = w * 16 + l15;
                out[((size_t)b * CV + c) * HW + p0 + q] = acc[qt][r] / sDenTot[q];
            }
    } else {
#pragma unroll
        for (int qt = 0; qt < 2; ++qt)
#pragma unroll
            for (int r = 0; r < 4; ++r) {
                const int q = qt * 16 + quad * 4 + r;
                const int c = w * 16 + l15;
                numW[((size_t)(s0 * NB + b) * HW + p0 + q) * CV + c] = acc[qt][r];
            }
    }
}

extern "C" void kernel_launch(void* const* d_in, const int* in_sizes, int n_in,
                              void* d_out, int out_size, void* d_ws, size_t ws_size,
                              hipStream_t stream) {
    const float* keys  = (const float*)d_in[0];
    const float* vals  = (const float*)d_in[1];
    const float* query = (const float*)d_in[2];
    const float* disp  = (const float*)d_in[3];
    const int*   seq   = (const int*)d_in[4];
    float* out = (float*)d_out;

    const size_t numElems = (size_t)SAI * NB * HW * CV;     // 2359296
    const size_t denElems = (size_t)SAI * NB * HW;          // 36864
    const size_t partBytes = (numElems + denElems) * sizeof(float);  // 9584640
    const size_t fragBytes = (size_t)SAI * NB * CK * HW * 2;         // 4718592 each
    const size_t needFull = partBytes + 3 * fragBytes;               // ~22.6 MiB

    float* numW = (float*)d_ws;
    float* denW = numW + numElems;

    if (ws_size >= needFull) {
        u16* khi = (u16*)((char*)d_ws + partBytes);
        u16* klo = (u16*)((char*)khi + fragBytes);
        u16* vbf = (u16*)((char*)klo + fragBytes);
        hipLaunchKernelGGL(cfa_prep, dim3(2 * SAI * NB * 8192 / 256), dim3(256), 0, stream,
                           keys, vals, khi, klo, vbf);
        hipLaunchKernelGGL(cfa_main, dim3(HW / 32, NB, SAI), dim3(256), 0, stream,
                           khi, klo, vbf, query, disp, seq, numW, denW);
        hipLaunchKernelGGL(cfa_reduce, dim3(1024), dim3(256), 0, stream,
                           numW, denW, out);
    } else if (ws_size >= partBytes) {
        hipLaunchKernelGGL(cfa_fb, dim3(HW / 32, NB, SAI), dim3(256), 0, stream,
                           keys, vals, query, disp, seq, numW, denW, (float*)nullptr, 1);
        hipLaunchKernelGGL(cfa_reduce, dim3(1024), dim3(256), 0, stream,
                           numW, denW, out);
    } else {
        hipLaunchKernelGGL(cfa_fb, dim3(HW / 32, NB, 1), dim3(256), 0, stream,
                           keys, vals, query, disp, seq,
                           (float*)nullptr, (float*)nullptr, out, SAI);
    }
}